// Round 1
// 593.008 us; speedup vs baseline: 1.1973x; 1.1973x over previous
//
#include <hip/hip_runtime.h>

// ---------------------------------------------------------------------------
// MoE top-2 of 8 experts, SwiGLU. B=2,S=2048 -> T=4096 tokens, H=1024, I=2816.
// fp64 gating (selection fidelity), bf16 MFMA grouped GEMMs on top-2 rows.
// R4: aux-path restructure (GEMM inner loops untouched — gemm1 is at the
// grouped-GEMM 2-phase structural ceiling ~835 TF, 8-phase upside ~5%):
//  - 3 transpose launches fused into one kernel (z=24), k_init folded in.
//  - rank assignment moved into k_gating (atomicAdd return = rank); k_build
//    and k_combine compute row = offs[e]+rank -> no atomics, no cur/slot_row.
//  - device-built tile list (e,m0) kills 8448+1536 null-block launches while
//    preserving the R3-measured n-fastest dispatch order (B-panel L2 reuse).
//  - gating x loads vectorized to float4 (fp64 accum swamps reorder).
// ---------------------------------------------------------------------------

namespace {
constexpr int TOKS = 4096;
constexpr int HDIM = 1024;
constexpr int IDIM = 2816;
constexpr int NEXP = 8;
constexpr int NROW = 8192;  // TOKS * 2 assignments

// workspace layout (bytes)
constexpr size_t WGT_OFF = 0;                         // bf16 Wg^T  [E][I][H]
constexpr size_t WUT_OFF = 46137344;                  // bf16 Wu^T  [E][I][H]
constexpr size_t WDT_OFF = 92274688;                  // bf16 Wd^T  [E][H][I]
constexpr size_t A_OFF   = 138412032;                 // bf16 A     [8192][H]
constexpr size_t ACT_OFF = 155189248;                 // bf16 act   [8192][I]
constexpr size_t CNT_OFF = 201326592;                 // int[8]
constexpr size_t OFS_OFF = CNT_OFF + 64;              // int[8]
constexpr size_t TLN_OFF = CNT_OFF + 128;             // int (tile count)
constexpr size_t TLS_OFF = CNT_OFF + 256;             // int2[96] tile list
constexpr size_t TIX_OFF = CNT_OFF + 1024;            // int4[4096] (e0,e1,r0,r1)
constexpr size_t TPR_OFF = CNT_OFF + 66560;           // float2[4096]
// ends at CNT_OFF + 99328 == previous layout's high-water mark
// partial fp32 [8192][H] aliases Wg^T region (GEMM1 done before GEMM2 writes)
constexpr size_t PRT_OFF = 0;                         // 33554432 <= 46137344
}  // namespace

typedef __attribute__((ext_vector_type(8))) short short8;
typedef __attribute__((ext_vector_type(8))) unsigned short ushort8;
typedef __attribute__((ext_vector_type(4))) float f32x4;

__device__ __forceinline__ unsigned short f2bf(float f) {
  union { float f; unsigned int u; } v; v.f = f;
  unsigned int u = v.u;
  return (unsigned short)((u + 0x7fffu + ((u >> 16) & 1u)) >> 16);  // RNE
}

__device__ __forceinline__ void gl2lds16(const void* g, void* l) {
  __builtin_amdgcn_global_load_lds(
      (const __attribute__((address_space(1))) void*)g,
      (__attribute__((address_space(3))) void*)l, 16, 0, 0);
}

// ------------- fused fp32 [R][C] -> bf16 [C][R] transpose (all 3 W) --------
// z: 0..7 = Wg expert e, 8..15 = Wu, 16..23 = Wd. 64x64 tiles, float4 reads,
// ushort8 stores. Block (0,0,0) also zeroes cnt[] (replaces k_init).
__global__ __launch_bounds__(256) void k_transpose_all(
    const float* __restrict__ Wg, const float* __restrict__ Wu,
    const float* __restrict__ Wd, unsigned short* __restrict__ WgT,
    unsigned short* __restrict__ WuT, unsigned short* __restrict__ WdT,
    int* __restrict__ cnt) {
  const int z = blockIdx.z;
  if (z == 0 && blockIdx.x == 0 && threadIdx.x < NEXP) cnt[threadIdx.x] = 0;
  const float* in; unsigned short* out; int C, R;
  if (z < 8)       { in = Wg; out = WgT; C = IDIM; R = HDIM; }
  else if (z < 16) { in = Wu; out = WuT; C = IDIM; R = HDIM; }
  else             { in = Wd; out = WdT; C = HDIM; R = IDIM; }
  const size_t eoff = (size_t)(z & 7) * HDIM * IDIM;
  in += eoff; out += eoff;
  const int nbx = C / 64;
  const int c0 = (blockIdx.x % nbx) * 64, r0 = (blockIdx.x / nbx) * 64;
  __shared__ float tile[64][65];
  const int tid = threadIdx.x;
  const int rr = tid >> 4, cc4 = (tid & 15) * 4;
#pragma unroll
  for (int i = 0; i < 4; ++i) {
    int r = rr + i * 16;
    float4 v = *(const float4*)(in + (size_t)(r0 + r) * C + c0 + cc4);
    tile[r][cc4 + 0] = v.x; tile[r][cc4 + 1] = v.y;
    tile[r][cc4 + 2] = v.z; tile[r][cc4 + 3] = v.w;
  }
  __syncthreads();
  const int j = tid & 7;  // 16B chunk within out row
#pragma unroll
  for (int i = 0; i < 2; ++i) {
    int c = (tid >> 3) + i * 32;
    ushort8 o;
#pragma unroll
    for (int k = 0; k < 8; ++k) o[k] = f2bf(tile[j * 8 + k][c]);
    *(ushort8*)(out + (size_t)(c0 + c) * R + r0 + j * 8) = o;
  }
}

// ------------------------------- gating ------------------------------------
// One wave per token. float4 x loads; fp64 accumulate + shuffle reduce.
// Lane 0 does top-2, softmax probs, and claims within-expert ranks via
// atomicAdd (overlapped with other waves' compute; removes k_build's
// serialized thread-0 atomic critical path).
__global__ __launch_bounds__(256) void k_gating(
    const float* __restrict__ x, const float* __restrict__ gw,
    float* __restrict__ logits_out, int* __restrict__ cnt,
    int4* __restrict__ tidx, float2* __restrict__ tprb) {
  const int lane = threadIdx.x & 63;
  const int t = blockIdx.x * 4 + (threadIdx.x >> 6);
  const float4* xr = (const float4*)(x + (size_t)t * HDIM);
  double acc[8];
#pragma unroll
  for (int e = 0; e < 8; ++e) acc[e] = 0.0;
#pragma unroll
  for (int jj = 0; jj < 4; ++jj) {
    float4 xv = xr[lane + jj * 64];
    const int hb = (lane + jj * 64) * 4;
    const float xs[4] = {xv.x, xv.y, xv.z, xv.w};
#pragma unroll
    for (int c = 0; c < 4; ++c) {
      const float4* g = (const float4*)(gw + (size_t)(hb + c) * 8);
      float4 g0 = g[0], g1 = g[1];
      acc[0] += (double)xs[c] * g0.x; acc[1] += (double)xs[c] * g0.y;
      acc[2] += (double)xs[c] * g0.z; acc[3] += (double)xs[c] * g0.w;
      acc[4] += (double)xs[c] * g1.x; acc[5] += (double)xs[c] * g1.y;
      acc[6] += (double)xs[c] * g1.z; acc[7] += (double)xs[c] * g1.w;
    }
  }
#pragma unroll
  for (int off = 32; off > 0; off >>= 1) {
#pragma unroll
    for (int e = 0; e < 8; ++e) acc[e] += __shfl_down(acc[e], off);
  }
  if (lane == 0) {
    float lg[8];
#pragma unroll
    for (int e = 0; e < 8; ++e) lg[e] = (float)acc[e];
#pragma unroll
    for (int e = 0; e < 8; ++e) logits_out[(size_t)t * 8 + e] = lg[e];
    float v0 = lg[0]; int i0 = 0; float v1 = -3.0e38f; int i1 = 0;
#pragma unroll
    for (int e = 1; e < 8; ++e) {
      if (lg[e] > v0) { v1 = v0; i1 = i0; v0 = lg[e]; i0 = e; }
      else if (lg[e] > v1) { v1 = lg[e]; i1 = e; }
    }
    float ex = expf(v1 - v0);
    float p0 = 1.0f / (1.0f + ex);
    float p1 = ex / (1.0f + ex);
    int r0 = atomicAdd(&cnt[i0], 1);   // within-expert rank
    int r1 = atomicAdd(&cnt[i1], 1);
    tidx[t] = make_int4(i0, i1, r0, r1);
    tprb[t] = make_float2(p0, p1);
  }
}

// ----------------- prefix scan + GEMM tile list (tiny) ---------------------
// tlist[i] = (expert, m0) for every live 128-row m-tile; max 71 entries.
__global__ void k_prefix(const int* __restrict__ cnt, int* __restrict__ offs,
                         int2* __restrict__ tlist, int* __restrict__ tln) {
  if (threadIdx.x == 0) {
    int s = 0, nt = 0;
    for (int e = 0; e < NEXP; ++e) {
      offs[e] = s;
      for (int m0 = 0; m0 < cnt[e]; m0 += 128) tlist[nt++] = make_int2(e, m0);
      s += cnt[e];
    }
    *tln = nt;
  }
}

// --------------- gather x rows to compact bf16 A (no atomics) --------------
__global__ __launch_bounds__(256) void k_build(
    const float* __restrict__ x, const int4* __restrict__ tidx,
    const int* __restrict__ offs, unsigned short* __restrict__ A) {
  const int t = blockIdx.x;
  const int4 ii = tidx[t];
  const int r0 = offs[ii.x] + ii.z, r1 = offs[ii.y] + ii.w;
  float4 v = ((const float4*)(x + (size_t)t * HDIM))[threadIdx.x];
  ushort4 b;
  b.x = f2bf(v.x); b.y = f2bf(v.y); b.z = f2bf(v.z); b.w = f2bf(v.w);
  ((ushort4*)(A + (size_t)r0 * HDIM))[threadIdx.x] = b;
  ((ushort4*)(A + (size_t)r1 * HDIM))[threadIdx.x] = b;
}

// ---------------- GEMM1: act = silu(A*Wg^T) * (A*Wu^T)  (bf16) -------------
// 128(M) x 64(N) tile, dual B, BK=64, 16x16x32 MFMA. XOR-swizzled LDS:
// LDS[row][chunk j] holds global chunk j^(row&7) (16B chunks) -> ds_read_b128
// is <=2-way instead of 16-way bank conflicted.
// Grid: n on blockIdx.x (fastest), tile list on blockIdx.y — keeps each B
// panel hot in one XCD's L2 (R2 measured the alternative: +85% FETCH).
__global__ __launch_bounds__(256, 2) void k_gemm1(
    const unsigned short* __restrict__ A, const unsigned short* __restrict__ WgT,
    const unsigned short* __restrict__ WuT, unsigned short* __restrict__ act,
    const int* __restrict__ cnt, const int* __restrict__ offs,
    const int2* __restrict__ tlist, const int* __restrict__ tln) {
  if ((int)blockIdx.y >= *tln) return;
  const int2 tl = tlist[blockIdx.y];
  const int e = tl.x, m0 = tl.y;
  const int ne = cnt[e];
  const int off = offs[e];
  const int n0 = blockIdx.x * 64;
  const unsigned short* Bg = WgT + ((size_t)e * IDIM + n0) * HDIM;
  const unsigned short* Bu = WuT + ((size_t)e * IDIM + n0) * HDIM;

  __shared__ unsigned short As[128 * 64];
  __shared__ unsigned short Bgs[64 * 64];
  __shared__ unsigned short Bus[64 * 64];

  const int tid = threadIdx.x, w = tid >> 6, lane = tid & 63;
  const int lrow8 = lane >> 3;                       // 0..7 row in 1KB chunk
  const int swz = ((lane & 7) ^ lrow8) * 8;          // swizzled src column
  const int m16 = lane & 15, quad = lane >> 4, l7 = lane & 7;

  f32x4 accg[2][4], accu[2][4];
#pragma unroll
  for (int mi = 0; mi < 2; ++mi)
#pragma unroll
    for (int ni = 0; ni < 4; ++ni) {
      accg[mi][ni] = (f32x4){0.f, 0.f, 0.f, 0.f};
      accu[mi][ni] = (f32x4){0.f, 0.f, 0.f, 0.f};
    }

  for (int kt = 0; kt < HDIM / 64; ++kt) {
    const int k0 = kt * 64;
#pragma unroll
    for (int i = 0; i < 4; ++i) {
      int gr = off + m0 + w * 32 + i * 8 + lrow8;
      gr = gr > (NROW - 1) ? (NROW - 1) : gr;
      gl2lds16(A + (size_t)gr * HDIM + k0 + swz, &As[(w * 32 + i * 8) * 64]);
    }
#pragma unroll
    for (int i = 0; i < 2; ++i) {
      int rl = w * 16 + i * 8 + lrow8;
      gl2lds16(Bg + (size_t)rl * HDIM + k0 + swz, &Bgs[(w * 16 + i * 8) * 64]);
      gl2lds16(Bu + (size_t)rl * HDIM + k0 + swz, &Bus[(w * 16 + i * 8) * 64]);
    }
    __syncthreads();
#pragma unroll
    for (int kk = 0; kk < 2; ++kk) {
      const int jc = ((kk * 4 + quad) ^ l7) * 8;     // swizzled read column
      short8 af[2], bgf[4], buf[4];
#pragma unroll
      for (int mi = 0; mi < 2; ++mi)
        af[mi] = *(const short8*)&As[(w * 32 + mi * 16 + m16) * 64 + jc];
#pragma unroll
      for (int ni = 0; ni < 4; ++ni) {
        bgf[ni] = *(const short8*)&Bgs[(ni * 16 + m16) * 64 + jc];
        buf[ni] = *(const short8*)&Bus[(ni * 16 + m16) * 64 + jc];
      }
#pragma unroll
      for (int mi = 0; mi < 2; ++mi)
#pragma unroll
        for (int ni = 0; ni < 4; ++ni) {
          accg[mi][ni] = __builtin_amdgcn_mfma_f32_16x16x32_bf16(
              af[mi], bgf[ni], accg[mi][ni], 0, 0, 0);
          accu[mi][ni] = __builtin_amdgcn_mfma_f32_16x16x32_bf16(
              af[mi], buf[ni], accu[mi][ni], 0, 0, 0);
        }
    }
    __syncthreads();
  }
  // epilogue: silu(g)*u -> bf16, staged through As for 16B stores
#pragma unroll
  for (int mi = 0; mi < 2; ++mi)
#pragma unroll
    for (int ni = 0; ni < 4; ++ni)
#pragma unroll
      for (int r = 0; r < 4; ++r) {
        int ml = w * 32 + mi * 16 + quad * 4 + r;
        float g = accg[mi][ni][r];
        float u = accu[mi][ni][r];
        float s = g / (1.0f + __expf(-g));
        As[ml * 64 + ni * 16 + m16] = f2bf(s * u);
      }
  __syncthreads();
#pragma unroll
  for (int i = 0; i < 4; ++i) {
    int chunk = i * 256 + tid;
    int row = chunk >> 3, j = chunk & 7;
    if (m0 + row < ne)
      *(ushort8*)&act[(size_t)(off + m0 + row) * IDIM + n0 + j * 8] =
          *(const ushort8*)&As[row * 64 + j * 8];
  }
}

// ---------------- GEMM2: partial = act * Wd^T  (bf16 -> fp32) --------------
// 128x128 tile, 4 waves 2x2, BK=64, XOR-swizzled LDS, n-fastest grid.
__global__ __launch_bounds__(256, 2) void k_gemm2(
    const unsigned short* __restrict__ act, const unsigned short* __restrict__ WdT,
    float* __restrict__ partial, const int* __restrict__ cnt,
    const int* __restrict__ offs, const int2* __restrict__ tlist,
    const int* __restrict__ tln) {
  if ((int)blockIdx.y >= *tln) return;
  const int2 tl = tlist[blockIdx.y];
  const int e = tl.x, m0 = tl.y;
  const int ne = cnt[e];
  const int off = offs[e];
  const int n0 = blockIdx.x * 128;
  const unsigned short* B = WdT + ((size_t)e * HDIM + n0) * IDIM;

  __shared__ unsigned short As[128 * 64];
  __shared__ unsigned short Bs[128 * 64];

  const int tid = threadIdx.x, w = tid >> 6, lane = tid & 63;
  const int lrow8 = lane >> 3;
  const int swz = ((lane & 7) ^ lrow8) * 8;
  const int m16 = lane & 15, quad = lane >> 4, l7 = lane & 7;
  const int wm = (w >> 1) * 64, wn = (w & 1) * 64;

  f32x4 acc[4][4];
#pragma unroll
  for (int mi = 0; mi < 4; ++mi)
#pragma unroll
    for (int ni = 0; ni < 4; ++ni) acc[mi][ni] = (f32x4){0.f, 0.f, 0.f, 0.f};

  for (int kt = 0; kt < IDIM / 64; ++kt) {
    const int k0 = kt * 64;
#pragma unroll
    for (int i = 0; i < 4; ++i) {
      int rl = w * 32 + i * 8 + lrow8;
      int gr = off + m0 + rl;
      gr = gr > (NROW - 1) ? (NROW - 1) : gr;
      gl2lds16(act + (size_t)gr * IDIM + k0 + swz, &As[(w * 32 + i * 8) * 64]);
      gl2lds16(B + (size_t)rl * IDIM + k0 + swz, &Bs[(w * 32 + i * 8) * 64]);
    }
    __syncthreads();
#pragma unroll
    for (int kk = 0; kk < 2; ++kk) {
      const int jc = ((kk * 4 + quad) ^ l7) * 8;
      short8 af[4], bf[4];
#pragma unroll
      for (int mi = 0; mi < 4; ++mi)
        af[mi] = *(const short8*)&As[(wm + mi * 16 + m16) * 64 + jc];
#pragma unroll
      for (int ni = 0; ni < 4; ++ni)
        bf[ni] = *(const short8*)&Bs[(wn + ni * 16 + m16) * 64 + jc];
#pragma unroll
      for (int mi = 0; mi < 4; ++mi)
#pragma unroll
        for (int ni = 0; ni < 4; ++ni)
          acc[mi][ni] = __builtin_amdgcn_mfma_f32_16x16x32_bf16(
              af[mi], bf[ni], acc[mi][ni], 0, 0, 0);
    }
    __syncthreads();
  }
#pragma unroll
  for (int mi = 0; mi < 4; ++mi)
#pragma unroll
    for (int ni = 0; ni < 4; ++ni)
#pragma unroll
      for (int r = 0; r < 4; ++r) {
        int ml = wm + mi * 16 + quad * 4 + r;
        if (m0 + ml < ne)
          partial[(size_t)(off + m0 + ml) * HDIM + n0 + wn + ni * 16 + m16] =
              acc[mi][ni][r];
      }
}

// ------------------- combine: out = p0*row0 + p1*row1 ----------------------
__global__ __launch_bounds__(256) void k_combine(
    const float* __restrict__ partial, const int4* __restrict__ tidx,
    const int* __restrict__ offs, const float2* __restrict__ tprb,
    float* __restrict__ out) {
  const int t = blockIdx.x;
  const int4 ii = tidx[t];
  const int r0 = offs[ii.x] + ii.z, r1 = offs[ii.y] + ii.w;
  const float2 p = tprb[t];
  float4 a = ((const float4*)(partial + (size_t)r0 * HDIM))[threadIdx.x];
  float4 b = ((const float4*)(partial + (size_t)r1 * HDIM))[threadIdx.x];
  float4 o;
  o.x = p.x * a.x + p.y * b.x;
  o.y = p.x * a.y + p.y * b.y;
  o.z = p.x * a.z + p.y * b.z;
  o.w = p.x * a.w + p.y * b.w;
  ((float4*)(out + (size_t)t * HDIM))[threadIdx.x] = o;
}

// ---------------------------------------------------------------------------
extern "C" void kernel_launch(void* const* d_in, const int* in_sizes, int n_in,
                              void* d_out, int out_size, void* d_ws, size_t ws_size,
                              hipStream_t stream) {
  const float* x  = (const float*)d_in[0];
  const float* gw = (const float*)d_in[1];
  const float* Wg = (const float*)d_in[2];
  const float* Wu = (const float*)d_in[3];
  const float* Wd = (const float*)d_in[4];
  float* out = (float*)d_out;
  char* ws = (char*)d_ws;

  unsigned short* WgT = (unsigned short*)(ws + WGT_OFF);
  unsigned short* WuT = (unsigned short*)(ws + WUT_OFF);
  unsigned short* WdT = (unsigned short*)(ws + WDT_OFF);
  unsigned short* A   = (unsigned short*)(ws + A_OFF);
  unsigned short* act = (unsigned short*)(ws + ACT_OFF);
  float* partial = (float*)(ws + PRT_OFF);
  int* cnt  = (int*)(ws + CNT_OFF);
  int* offs = (int*)(ws + OFS_OFF);
  int* tln  = (int*)(ws + TLN_OFF);
  int2* tlist = (int2*)(ws + TLS_OFF);
  int4* tidx = (int4*)(ws + TIX_OFF);
  float2* tprb = (float2*)(ws + TPR_OFF);

  float* logits_out = out + (size_t)TOKS * HDIM;  // output 1 region

  // Wg,Wu: [H][I] -> [I][H]; Wd: [I][H] -> [H][I]; also zeroes cnt[]
  k_transpose_all<<<dim3(704, 1, 24), 256, 0, stream>>>(Wg, Wu, Wd, WgT, WuT,
                                                        WdT, cnt);
  k_gating<<<TOKS / 4, 256, 0, stream>>>(x, gw, logits_out, cnt, tidx, tprb);
  k_prefix<<<1, 64, 0, stream>>>(cnt, offs, tlist, tln);
  k_build<<<TOKS, 256, 0, stream>>>(x, tidx, offs, A);
  k_gemm1<<<dim3(IDIM / 64, 72), 256, 0, stream>>>(A, WgT, WuT, act, cnt, offs,
                                                   tlist, tln);
  k_gemm2<<<dim3(HDIM / 128, 72), 256, 0, stream>>>(act, WdT, partial, cnt,
                                                    offs, tlist, tln);
  k_combine<<<TOKS, 256, 0, stream>>>(partial, tidx, offs, tprb, out);
}